// Round 14
// baseline (1355.889 us; speedup 1.0000x reference)
//
#include <hip/hip_runtime.h>
#include <stdint.h>

// TernaryMLP: relu-chain of h @ (gamma*T).T + b, T ternary (exact in bf16).
// gamma via deterministic fp64 2-stage reduction; bf16 MFMA GEMMs.
// Layers 1-3: 256^2-tile GEMM, 16x16x32 MFMA, 1 barrier/K-tile.
//   R14: B (weights, L2/L3-resident) loaded DIRECTLY from global into
//   fragments (16x64B fully-consumed segments, L1-shared across wc pairs);
//   only A staged in LDS (64KB double-buffer). Cuts LDS-port traffic
//   ~2800->~1800 cyc/K-tile. No setprio (R13); walls after lgkm only.
// Layer 4 (N=1024): 128^2 2-phase GEMM with XOR swizzle.
// Aux: cvt_bf16 fused into the absmean launch (blockIdx.y==4).

#define EPSQ 1e-5f

typedef __attribute__((ext_vector_type(8))) short bf16x8;   // 8 bf16 = 4 VGPR
typedef __attribute__((ext_vector_type(4))) float f32x4;    // MFMA accum

__device__ __forceinline__ uint16_t f2bf(float f) {
    uint32_t u = __float_as_uint(f);
    return (uint16_t)((u + 0x7FFFu + ((u >> 16) & 1u)) >> 16);
}

__device__ __forceinline__ void load_lds16(const uint16_t* g, char* l) {
    __builtin_amdgcn_global_load_lds((const __attribute__((address_space(1))) void*)g,
                                     (__attribute__((address_space(3))) void*)l,
                                     16, 0, 0);
}

// ---- gamma = mean(|W|) stage1 for 4 matrices + x->bf16 cvt, one launch ----
__global__ void absmean4_cvt(const float* __restrict__ w0, const float* __restrict__ w1,
                             const float* __restrict__ w2, const float* __restrict__ w3,
                             double* __restrict__ partial,
                             const float* __restrict__ x, uint16_t* __restrict__ y) {
    const int mi = blockIdx.y;
    if (mi == 4) {  // cvt branch: x (fp32, 33.5M) -> y (bf16)
        const long long n = 33554432LL;
        const long long stride = (long long)gridDim.x * blockDim.x * 4;
        for (long long i = ((long long)blockIdx.x * blockDim.x + threadIdx.x) * 4;
             i < n; i += stride) {
            float4 v = *(const float4*)(x + i);
            ushort4 o;
            o.x = f2bf(v.x); o.y = f2bf(v.y); o.z = f2bf(v.z); o.w = f2bf(v.w);
            *(ushort4*)(y + i) = o;
        }
        return;
    }
    const float* w = (mi == 0) ? w0 : (mi == 1) ? w1 : (mi == 2) ? w2 : w3;
    const long long n = (mi == 3) ? 4096000LL : 16777216LL;
    double acc = 0.0;
    const long long tid = (long long)blockIdx.x * blockDim.x + threadIdx.x;
    const long long stride = (long long)gridDim.x * blockDim.x;
    const float4* w4 = (const float4*)w;
    const long long n4 = n >> 2;
    for (long long i = tid; i < n4; i += stride) {
        float4 v = w4[i];
        acc += (double)fabsf(v.x) + (double)fabsf(v.y) +
               (double)fabsf(v.z) + (double)fabsf(v.w);
    }
    __shared__ double sm[256];
    sm[threadIdx.x] = acc;
    __syncthreads();
    for (int s = 128; s > 0; s >>= 1) {
        if ((int)threadIdx.x < s) sm[threadIdx.x] += sm[threadIdx.x + s];
        __syncthreads();
    }
    if (threadIdx.x == 0) partial[mi * 512 + blockIdx.x] = sm[0];
}

__global__ void absmean_stage2(const double* __restrict__ partial,
                               float* __restrict__ gammas) {
    const int m = blockIdx.x;
    __shared__ double sm[256];
    double acc = partial[m * 512 + threadIdx.x] + partial[m * 512 + 256 + threadIdx.x];
    sm[threadIdx.x] = acc;
    __syncthreads();
    for (int s = 128; s > 0; s >>= 1) {
        if ((int)threadIdx.x < s) sm[threadIdx.x] += sm[threadIdx.x + s];
        __syncthreads();
    }
    if (threadIdx.x == 0) {
        const double n = (m == 3) ? 1000.0 * 4096.0 : 4096.0 * 4096.0;
        gammas[m] = (float)(sm[0] / n);
    }
}

// ---------------- quantize W -> ternary bf16 (+ zero padding rows) ----------------
__global__ void quantize_w(const float* __restrict__ w, uint16_t* __restrict__ q,
                           long long n_valid, long long n_total,
                           const float* __restrict__ gammas, int gi) {
    const float d = gammas[gi] + EPSQ;
    const long long stride = (long long)gridDim.x * blockDim.x * 4;
    for (long long i = ((long long)blockIdx.x * blockDim.x + threadIdx.x) * 4;
         i < n_total; i += stride) {
        float4 v = make_float4(0.f, 0.f, 0.f, 0.f);
        if (i < n_valid) v = *(const float4*)(w + i);
        ushort4 o;
        o.x = f2bf(fminf(1.f, fmaxf(-1.f, rintf(v.x / d))));
        o.y = f2bf(fminf(1.f, fmaxf(-1.f, rintf(v.y / d))));
        o.z = f2bf(fminf(1.f, fmaxf(-1.f, rintf(v.z / d))));
        o.w = f2bf(fminf(1.f, fmaxf(-1.f, rintf(v.w / d))));
        *(ushort4*)(q + i) = o;
    }
}

// ===== 256x256-tile GEMM, A-in-LDS + B-direct-from-global (layers 1-3) =====
// C[m][n] = epi(gamma * sum_k A[m][k]*Bt[n][k] + bias[n])
// 512 thr = 8 waves (2M x 4N), per-wave 128x64 via 8x4 frags of 16x16.
// LDS 64KB: buf[2] x A (256x64 bf16, XOR-swizzled). B frags loaded straight
// from global: lane reads 16B at row (wc*64+n*16+(lane&15)), col kk*32 +
// (lane>>4)*8 -> 16x64B fully-consumed segments, L3-resident weights.
// Tile t: B loads (8) -> A kk0 ds_reads -> stage A(t+1) -> lgkm0 -> 32 MFMA
// -> A kk1 reads -> lgkm0 -> 32 MFMA -> vmcnt(0) -> barrier.
template<bool RELU, bool BF16OUT>
__global__ __launch_bounds__(512, 2) void gemm256(
    const uint16_t* __restrict__ A, const uint16_t* __restrict__ Bt,
    const float* __restrict__ bias, const float* __restrict__ gammas, int gi,
    void* __restrict__ Cp, int K, int Nstore, int Nvalid, int gridN)
{
    __shared__ char lds[65536];

    const int tid  = threadIdx.x;
    const int lane = tid & 63;
    const int wid  = tid >> 6;
    const int wr   = wid >> 2;     // 0..1  -> A-half, C row block
    const int wc   = wid & 3;      // 0..3  -> C col block

    // T1: bijective XCD swizzle (gridDim.x % 8 == 0)
    const int nwg = gridDim.x;
    const int logical = ((int)blockIdx.x & 7) * (nwg >> 3) + ((int)blockIdx.x >> 3);
    const long long tileM = (long long)(logical / gridN) * 256;
    const long long tileN = (long long)(logical % gridN) * 256;

    // ---- A staging (inverse-swizzled global source, linear LDS dest) ----
    // one issue: 512 thr x 16B = 8KB = 64 rows x 128B
    const int srow = tid >> 3;                                   // 0..63
    const int scol = (((tid & 7) ^ ((tid >> 3) & 7)) << 3);      // element offset
    const uint16_t* As = A + (tileM + srow) * (long long)K + scol;

    auto stageA = [&](int par, int k0) {
        char* base = lds + par * 32768 + wid * 1024;
#pragma unroll
        for (int i = 0; i < 4; ++i)
            load_lds16(As + (long long)(i * 64) * K + k0, base + i * 8192);
    };

    // ---- A fragment read addressing (16x16x32: row=lane&15, kq=lane>>4) ----
    const int lr   = lane & 15;
    const int cb0  = (lane >> 4) << 4;        // 0,16,32,48 (k-quarter byte)
    const int swz  = (lane & 7) << 4;
    const int colk0 = cb0 ^ swz;
    const int colk1 = (cb0 | 64) ^ swz;
    const int Aoff = wr * 16384 + lr * 128;

    // ---- B direct-load addressing ----
    const uint16_t* Bg = Bt + (tileN + wc * 64 + lr) * (long long)K +
                         ((lane >> 4) << 3);   // + n*16*K + t*64 (+32 for kk1)

    f32x4 acc[8][4];
#pragma unroll
    for (int m = 0; m < 8; ++m)
#pragma unroll
        for (int n = 0; n < 4; ++n)
            acc[m][n] = (f32x4){0.f, 0.f, 0.f, 0.f};

    const int NT = K >> 6;   // 64 K-tiles

    // ---- prologue: stage A(t0), drain, barrier ----
    stageA(0, 0);
    asm volatile("s_waitcnt vmcnt(0)" ::: "memory");
    __builtin_amdgcn_s_barrier();

    for (int t = 0; t < NT; ++t) {
        const int par = t & 1;
        const char* Ab = lds + par * 32768 + Aoff;
        const uint16_t* Bk = Bg + (long long)t * 64;

        // B fragment loads (global; compiler inserts the counted vmcnt)
        bf16x8 bg0[4], bg1[4];
#pragma unroll
        for (int n = 0; n < 4; ++n)
            bg0[n] = *(const bf16x8*)(Bk + (long long)(n * 16) * K);
#pragma unroll
        for (int n = 0; n < 4; ++n)
            bg1[n] = *(const bf16x8*)(Bk + (long long)(n * 16) * K + 32);

        bf16x8 a[8];
        // A kk0 reads
#pragma unroll
        for (int m = 0; m < 8; ++m)
            a[m] = *(const bf16x8*)(Ab + m * 2048 + colk0);

        // next-tile A staging issues under the lgkm wait (WAR-safe:
        // buf^1's reads completed before the previous tile-end barrier)
        if (t + 1 < NT) stageA(par ^ 1, (t + 1) * 64);

        asm volatile("s_waitcnt lgkmcnt(0)" ::: "memory");
        __builtin_amdgcn_sched_barrier(0);   // rule #18 wall
#pragma unroll
        for (int m = 0; m < 8; ++m)
#pragma unroll
            for (int n = 0; n < 4; ++n)
                acc[m][n] = __builtin_amdgcn_mfma_f32_16x16x32_bf16(
                    a[m], bg0[n], acc[m][n], 0, 0, 0);
        // (no wall: kk1 A-reads may hoist into cluster0's tail)

        bf16x8 a2[8];
#pragma unroll
        for (int m = 0; m < 8; ++m)
            a2[m] = *(const bf16x8*)(Ab + m * 2048 + colk1);
        asm volatile("s_waitcnt lgkmcnt(0)" ::: "memory");
        __builtin_amdgcn_sched_barrier(0);   // rule #18 wall
#pragma unroll
        for (int m = 0; m < 8; ++m)
#pragma unroll
            for (int n = 0; n < 4; ++n)
                acc[m][n] = __builtin_amdgcn_mfma_f32_16x16x32_bf16(
                    a2[m], bg1[n], acc[m][n], 0, 0, 0);

        // publish next tile's A (loads issued a full tile ago)
        if (t + 1 < NT)
            asm volatile("s_waitcnt vmcnt(0)" ::: "memory");
        __builtin_amdgcn_sched_barrier(0);
        __builtin_amdgcn_s_barrier();
    }

    // ---- epilogue: C/D 16x16: col=lane&15, row=(lane>>4)*4+j ----
    const float g = gammas[gi];
    const int cr = (lane >> 4) << 2;
    const int cc = lane & 15;
#pragma unroll
    for (int m = 0; m < 8; ++m) {
        const long long row = tileM + wr * 128 + m * 16 + cr;
#pragma unroll
        for (int n = 0; n < 4; ++n) {
            const int col = (int)tileN + wc * 64 + n * 16 + cc;
            if (col < Nvalid) {
                const float bb = bias[col];
#pragma unroll
                for (int j = 0; j < 4; ++j) {
                    float v = acc[m][n][j] * g + bb;
                    if (RELU) v = fmaxf(v, 0.f);
                    if (BF16OUT)
                        ((uint16_t*)Cp)[(row + j) * (long long)Nstore + col] = f2bf(v);
                    else
                        ((float*)Cp)[(row + j) * (long long)Nstore + col] = v;
                }
            }
        }
    }
}

// ================= 128x128-tile GEMM with swizzle (layer 4) =================
template<bool RELU, bool BF16OUT>
__global__ __launch_bounds__(256) void gemm_bt(
    const uint16_t* __restrict__ A, const uint16_t* __restrict__ Bt,
    const float* __restrict__ bias, const float* __restrict__ gammas, int gi,
    void* __restrict__ Cp, int K, int Nstore, int Nvalid)
{
    constexpr int BK = 64;
    __shared__ char Atile[128 * 128];
    __shared__ char Btile[128 * 128];

    const int tid  = threadIdx.x;
    const int lane = tid & 63;
    const int wv   = tid >> 6;
    const int wr   = wv >> 1, wc = wv & 1;
    const long long tileM = (long long)blockIdx.y * 128;
    const long long tileN = (long long)blockIdx.x * 128;

    const float g = gammas[gi];

    f32x4 acc[4][4];
#pragma unroll
    for (int m = 0; m < 4; ++m)
#pragma unroll
        for (int n = 0; n < 4; ++n)
            acc[m][n] = (f32x4){0.f, 0.f, 0.f, 0.f};

    const int sr = tid >> 3;
    const int sc = ((tid & 7) * 8) ^ (((tid >> 3) & 7) * 8);
    const uint16_t* Ag = A  + (tileM + sr) * K + sc;
    const uint16_t* Bg = Bt + (tileN + sr) * K + sc;
    char* Ad = Atile + tid * 16;
    char* Bd = Btile + tid * 16;

    const int lr = lane & 15;
    const int klane = (lane >> 4) * 16;
    const int swz = (lr & 7) << 4;

    const int kIters = K / BK;
    for (int kt = 0; kt < kIters; ++kt) {
        const long long k0 = (long long)kt * BK;
        __syncthreads();
#pragma unroll
        for (int i = 0; i < 4; ++i) {
            load_lds16(Ag + (long long)(i * 32) * K + k0, Ad + i * 4096);
            load_lds16(Bg + (long long)(i * 32) * K + k0, Bd + i * 4096);
        }
        __syncthreads();
#pragma unroll
        for (int kk2 = 0; kk2 < 2; ++kk2) {
            const int cb = (kk2 * 64 + klane) ^ swz;
            bf16x8 a[4], b[4];
#pragma unroll
            for (int m = 0; m < 4; ++m)
                a[m] = *(const bf16x8*)(Atile + (wr * 64 + m * 16 + lr) * 128 + cb);
#pragma unroll
            for (int n = 0; n < 4; ++n)
                b[n] = *(const bf16x8*)(Btile + (wc * 64 + n * 16 + lr) * 128 + cb);
#pragma unroll
            for (int m = 0; m < 4; ++m)
#pragma unroll
                for (int n = 0; n < 4; ++n)
                    acc[m][n] = __builtin_amdgcn_mfma_f32_16x16x32_bf16(
                        a[m], b[n], acc[m][n], 0, 0, 0);
        }
    }

    const int cr = (lane >> 4) * 4;
    const int cc = lane & 15;
#pragma unroll
    for (int m = 0; m < 4; ++m) {
        const long long row = tileM + wr * 64 + m * 16 + cr;
#pragma unroll
        for (int n = 0; n < 4; ++n) {
            const int col = (int)tileN + wc * 64 + n * 16 + cc;
            if (col < Nvalid) {
                const float bb = bias[col];
#pragma unroll
                for (int j = 0; j < 4; ++j) {
                    float v = acc[m][n][j] * g + bb;
                    if (RELU) v = fmaxf(v, 0.f);
                    if (BF16OUT)
                        ((uint16_t*)Cp)[(row + j) * (long long)Nstore + col] = f2bf(v);
                    else
                        ((float*)Cp)[(row + j) * (long long)Nstore + col] = v;
                }
            }
        }
    }
}

extern "C" void kernel_launch(void* const* d_in, const int* in_sizes, int n_in,
                              void* d_out, int out_size, void* d_ws, size_t ws_size,
                              hipStream_t stream) {
    const float* x  = (const float*)d_in[0];
    const float* W1 = (const float*)d_in[1];
    const float* b1 = (const float*)d_in[2];
    const float* W2 = (const float*)d_in[3];
    const float* b2 = (const float*)d_in[4];
    const float* W3 = (const float*)d_in[5];
    const float* b3 = (const float*)d_in[6];
    const float* W4 = (const float*)d_in[7];
    const float* b4 = (const float*)d_in[8];
    float* out = (float*)d_out;

    const long long B = 8192, D = 4096, H = 4096, C = 1000, CPAD = 1024;

    char* ws = (char*)d_ws;
    float*  gammas  = (float*)ws;
    double* partial = (double*)(ws + 256);
    uint16_t* Q  = (uint16_t*)(ws + 32768);
    uint16_t* HA = Q  + (size_t)(H * H);
    uint16_t* HB = HA + (size_t)(B * H);

    const long long nW  = H * D;
    const long long nW4 = C * D;

    // stage1 abs-means (4 matrices) + x->bf16 cvt, fused into one launch
    absmean4_cvt<<<dim3(512, 5), 256, 0, stream>>>(W1, W2, W3, W4, partial, x, HA);
    absmean_stage2<<<4, 256, 0, stream>>>(partial, gammas);

    const int gridN = (int)(H / 256);           // 16
    const int nwg   = gridN * (int)(B / 256);   // 512

    quantize_w<<<2048, 256, 0, stream>>>(W1, Q, nW, nW, gammas, 0);
    gemm256<true, true><<<dim3(nwg), dim3(512), 0, stream>>>(
        HA, Q, b1, gammas, 0, HB, (int)D, (int)H, (int)H, gridN);
    quantize_w<<<2048, 256, 0, stream>>>(W2, Q, nW, nW, gammas, 1);
    gemm256<true, true><<<dim3(nwg), dim3(512), 0, stream>>>(
        HB, Q, b2, gammas, 1, HA, (int)H, (int)H, (int)H, gridN);
    quantize_w<<<2048, 256, 0, stream>>>(W3, Q, nW, nW, gammas, 2);
    gemm256<true, true><<<dim3(nwg), dim3(512), 0, stream>>>(
        HA, Q, b3, gammas, 2, HB, (int)H, (int)H, (int)H, gridN);
    quantize_w<<<2048, 256, 0, stream>>>(W4, Q, nW4, CPAD * D, gammas, 3);
    gemm_bt<false, false><<<dim3((unsigned)(CPAD / 128), (unsigned)(B / 128)),
                            dim3(256), 0, stream>>>(
        HB, Q, b4, gammas, 3, out, (int)H, (int)C, (int)C);
}

// Round 15
// 833.576 us; speedup vs baseline: 1.6266x; 1.6266x over previous
//
#include <hip/hip_runtime.h>
#include <stdint.h>

// TernaryMLP: relu-chain of h @ (gamma*T).T + b, T ternary (exact in bf16).
// gamma via deterministic fp64 2-stage reduction; bf16 MFMA GEMMs.
// Layers 1-3: 256^2-tile GEMM, 16x16x32 MFMA, 1 barrier/K-tile (R13 base:
//   no setprio, kk1 reads hoist into cluster0). R15: cluster1 ROTATED across
//   the tile-end barrier -> executes in the next iteration's post-barrier
//   region, overlapping next-tile kk0 ds_reads + staging issue (register-only
//   MFMA is barrier-legal). Same register footprint as R13.
// Layer 4 (N=1024): 128^2 2-phase GEMM with XOR swizzle.
// Aux: cvt_bf16 fused into the absmean launch (blockIdx.y==4).

#define EPSQ 1e-5f

typedef __attribute__((ext_vector_type(8))) short bf16x8;   // 8 bf16 = 4 VGPR
typedef __attribute__((ext_vector_type(4))) float f32x4;    // MFMA accum

__device__ __forceinline__ uint16_t f2bf(float f) {
    uint32_t u = __float_as_uint(f);
    return (uint16_t)((u + 0x7FFFu + ((u >> 16) & 1u)) >> 16);
}

__device__ __forceinline__ void load_lds16(const uint16_t* g, char* l) {
    __builtin_amdgcn_global_load_lds((const __attribute__((address_space(1))) void*)g,
                                     (__attribute__((address_space(3))) void*)l,
                                     16, 0, 0);
}

// ---- gamma = mean(|W|) stage1 for 4 matrices + x->bf16 cvt, one launch ----
__global__ void absmean4_cvt(const float* __restrict__ w0, const float* __restrict__ w1,
                             const float* __restrict__ w2, const float* __restrict__ w3,
                             double* __restrict__ partial,
                             const float* __restrict__ x, uint16_t* __restrict__ y) {
    const int mi = blockIdx.y;
    if (mi == 4) {  // cvt branch: x (fp32, 33.5M) -> y (bf16)
        const long long n = 33554432LL;
        const long long stride = (long long)gridDim.x * blockDim.x * 4;
        for (long long i = ((long long)blockIdx.x * blockDim.x + threadIdx.x) * 4;
             i < n; i += stride) {
            float4 v = *(const float4*)(x + i);
            ushort4 o;
            o.x = f2bf(v.x); o.y = f2bf(v.y); o.z = f2bf(v.z); o.w = f2bf(v.w);
            *(ushort4*)(y + i) = o;
        }
        return;
    }
    const float* w = (mi == 0) ? w0 : (mi == 1) ? w1 : (mi == 2) ? w2 : w3;
    const long long n = (mi == 3) ? 4096000LL : 16777216LL;
    double acc = 0.0;
    const long long tid = (long long)blockIdx.x * blockDim.x + threadIdx.x;
    const long long stride = (long long)gridDim.x * blockDim.x;
    const float4* w4 = (const float4*)w;
    const long long n4 = n >> 2;
    for (long long i = tid; i < n4; i += stride) {
        float4 v = w4[i];
        acc += (double)fabsf(v.x) + (double)fabsf(v.y) +
               (double)fabsf(v.z) + (double)fabsf(v.w);
    }
    __shared__ double sm[256];
    sm[threadIdx.x] = acc;
    __syncthreads();
    for (int s = 128; s > 0; s >>= 1) {
        if ((int)threadIdx.x < s) sm[threadIdx.x] += sm[threadIdx.x + s];
        __syncthreads();
    }
    if (threadIdx.x == 0) partial[mi * 512 + blockIdx.x] = sm[0];
}

__global__ void absmean_stage2(const double* __restrict__ partial,
                               float* __restrict__ gammas) {
    const int m = blockIdx.x;
    __shared__ double sm[256];
    double acc = partial[m * 512 + threadIdx.x] + partial[m * 512 + 256 + threadIdx.x];
    sm[threadIdx.x] = acc;
    __syncthreads();
    for (int s = 128; s > 0; s >>= 1) {
        if ((int)threadIdx.x < s) sm[threadIdx.x] += sm[threadIdx.x + s];
        __syncthreads();
    }
    if (threadIdx.x == 0) {
        const double n = (m == 3) ? 1000.0 * 4096.0 : 4096.0 * 4096.0;
        gammas[m] = (float)(sm[0] / n);
    }
}

// ---------------- quantize W -> ternary bf16 (+ zero padding rows) ----------------
__global__ void quantize_w(const float* __restrict__ w, uint16_t* __restrict__ q,
                           long long n_valid, long long n_total,
                           const float* __restrict__ gammas, int gi) {
    const float d = gammas[gi] + EPSQ;
    const long long stride = (long long)gridDim.x * blockDim.x * 4;
    for (long long i = ((long long)blockIdx.x * blockDim.x + threadIdx.x) * 4;
         i < n_total; i += stride) {
        float4 v = make_float4(0.f, 0.f, 0.f, 0.f);
        if (i < n_valid) v = *(const float4*)(w + i);
        ushort4 o;
        o.x = f2bf(fminf(1.f, fmaxf(-1.f, rintf(v.x / d))));
        o.y = f2bf(fminf(1.f, fmaxf(-1.f, rintf(v.y / d))));
        o.z = f2bf(fminf(1.f, fmaxf(-1.f, rintf(v.z / d))));
        o.w = f2bf(fminf(1.f, fmaxf(-1.f, rintf(v.w / d))));
        *(ushort4*)(q + i) = o;
    }
}

// ============ 256x256-tile GEMM, rotated pipeline (layers 1-3) ============
// C[m][n] = epi(gamma * sum_k A[m][k]*Bt[n][k] + bias[n])
// 512 thr = 8 waves (2M x 4N), per-wave 128x64 via 8x4 frags of 16x16.
// LDS 128KB: buf[2] x {A:32KB, B:32KB} of 256x64 bf16.
// Swizzle: LDS[r][cb] holds global[r][cb ^ ((r&7)<<4)].
// Loop body (wall-free regions in brackets):
//   [cluster1(t-1) || kk0(t) ds_reads || stage(t+1)] lgkm0,WALL
//   [cluster0(t) || kk1(t) ds_reads] lgkm0,WALL vmcnt(0) barrier
// Final cluster1 after the loop.
template<bool RELU, bool BF16OUT>
__global__ __launch_bounds__(512, 2) void gemm256(
    const uint16_t* __restrict__ A, const uint16_t* __restrict__ Bt,
    const float* __restrict__ bias, const float* __restrict__ gammas, int gi,
    void* __restrict__ Cp, int K, int Nstore, int Nvalid, int gridN)
{
    __shared__ char lds[131072];

    const int tid  = threadIdx.x;
    const int lane = tid & 63;
    const int wid  = tid >> 6;
    const int wr   = wid >> 2;     // 0..1  -> A-half, C row block
    const int wc   = wid & 3;      // 0..3  -> C col block

    // T1: bijective XCD swizzle (gridDim.x % 8 == 0)
    const int nwg = gridDim.x;
    const int logical = ((int)blockIdx.x & 7) * (nwg >> 3) + ((int)blockIdx.x >> 3);
    const long long tileM = (long long)(logical / gridN) * 256;
    const long long tileN = (long long)(logical % gridN) * 256;

    // ---- staging (inverse-swizzled global source, linear LDS dest) ----
    const int srow = tid >> 3;
    const int scol = (((tid & 7) ^ ((tid >> 3) & 7)) << 3);
    const uint16_t* As = A  + (tileM + srow) * (long long)K + scol;
    const uint16_t* Bs = Bt + (tileN + srow) * (long long)K + scol;

    auto stageAll = [&](int par, int k0) {
        char* base = lds + par * 65536;
#pragma unroll
        for (int h = 0; h < 2; ++h) {
            const uint16_t* sa = As + (long long)(h * 128) * K + k0;
            char* da = base + h * 16384 + wid * 1024;
            load_lds16(sa, da);
            load_lds16(sa + (long long)64 * K, da + 8192);
            const uint16_t* sb = Bs + (long long)(h * 128) * K + k0;
            char* db = base + 32768 + h * 16384 + wid * 1024;
            load_lds16(sb, db);
            load_lds16(sb + (long long)64 * K, db + 8192);
        }
    };

    // ---- fragment read addressing (16x16x32: row=lane&15, kq=lane>>4) ----
    const int lr   = lane & 15;
    const int cb0  = (lane >> 4) << 4;        // 0,16,32,48 (k-quarter byte)
    const int swz  = (lane & 7) << 4;
    const int colk0 = cb0 ^ swz;
    const int colk1 = (cb0 | 64) ^ swz;
    const int Aoff = wr * 16384 + lr * 128;
    const int Boff = 32768 + (wc >> 1) * 16384 + ((wc & 1) * 64 + lr) * 128;

    f32x4 acc[8][4];
#pragma unroll
    for (int m = 0; m < 8; ++m)
#pragma unroll
        for (int n = 0; n < 4; ++n)
            acc[m][n] = (f32x4){0.f, 0.f, 0.f, 0.f};

    const int NT = K >> 6;   // 64 K-tiles

    // ---- prologue: stage t0, drain, barrier ----
    stageAll(0, 0);
    asm volatile("s_waitcnt vmcnt(0)" ::: "memory");
    __builtin_amdgcn_s_barrier();

    bf16x8 a[8], b[4], a2[8], b2[4];

    for (int t = 0; t < NT; ++t) {
        const int par = t & 1;
        const char* Ab = lds + par * 65536 + Aoff;
        const char* Bb = lds + par * 65536 + Boff;

        // ==== region A (wall-free): kk0(t) reads || stage(t+1) || cluster1(t-1)
#pragma unroll
        for (int n = 0; n < 4; ++n)
            b[n] = *(const bf16x8*)(Bb + n * 2048 + colk0);
#pragma unroll
        for (int m = 0; m < 8; ++m)
            a[m] = *(const bf16x8*)(Ab + m * 2048 + colk0);
        if (t + 1 < NT) stageAll(par ^ 1, (t + 1) * 64);
        if (t > 0) {
            // cluster1 of tile t-1 (register-only; overlaps the reads above)
#pragma unroll
            for (int m = 0; m < 8; ++m)
#pragma unroll
                for (int n = 0; n < 4; ++n)
                    acc[m][n] = __builtin_amdgcn_mfma_f32_16x16x32_bf16(
                        a2[m], b2[n], acc[m][n], 0, 0, 0);
        }
        asm volatile("s_waitcnt lgkmcnt(0)" ::: "memory");
        __builtin_amdgcn_sched_barrier(0);   // rule #18 wall

        // ==== region B (wall-free): cluster0(t) || kk1(t) reads
#pragma unroll
        for (int m = 0; m < 8; ++m)
#pragma unroll
            for (int n = 0; n < 4; ++n)
                acc[m][n] = __builtin_amdgcn_mfma_f32_16x16x32_bf16(
                    a[m], b[n], acc[m][n], 0, 0, 0);
#pragma unroll
        for (int n = 0; n < 4; ++n)
            b2[n] = *(const bf16x8*)(Bb + n * 2048 + colk1);
#pragma unroll
        for (int m = 0; m < 8; ++m)
            a2[m] = *(const bf16x8*)(Ab + m * 2048 + colk1);
        asm volatile("s_waitcnt lgkmcnt(0)" ::: "memory");
        __builtin_amdgcn_sched_barrier(0);   // rule #18 wall (cluster1 is
                                             // next-iter, post-barrier)
        // publish next tile's staging; kk1 reads are drained (lgkm above),
        // so stage(t+2) next iteration is WAR-safe on this buffer
        if (t + 1 < NT)
            asm volatile("s_waitcnt vmcnt(0)" ::: "memory");
        __builtin_amdgcn_s_barrier();
    }

    // ---- final cluster1 (tile NT-1) ----
#pragma unroll
    for (int m = 0; m < 8; ++m)
#pragma unroll
        for (int n = 0; n < 4; ++n)
            acc[m][n] = __builtin_amdgcn_mfma_f32_16x16x32_bf16(
                a2[m], b2[n], acc[m][n], 0, 0, 0);

    // ---- epilogue: C/D 16x16: col=lane&15, row=(lane>>4)*4+j ----
    const float g = gammas[gi];
    const int cr = (lane >> 4) << 2;
    const int cc = lane & 15;
#pragma unroll
    for (int m = 0; m < 8; ++m) {
        const long long row = tileM + wr * 128 + m * 16 + cr;
#pragma unroll
        for (int n = 0; n < 4; ++n) {
            const int col = (int)tileN + wc * 64 + n * 16 + cc;
            if (col < Nvalid) {
                const float bb = bias[col];
#pragma unroll
                for (int j = 0; j < 4; ++j) {
                    float v = acc[m][n][j] * g + bb;
                    if (RELU) v = fmaxf(v, 0.f);
                    if (BF16OUT)
                        ((uint16_t*)Cp)[(row + j) * (long long)Nstore + col] = f2bf(v);
                    else
                        ((float*)Cp)[(row + j) * (long long)Nstore + col] = v;
                }
            }
        }
    }
}

// ================= 128x128-tile GEMM with swizzle (layer 4) =================
template<bool RELU, bool BF16OUT>
__global__ __launch_bounds__(256) void gemm_bt(
    const uint16_t* __restrict__ A, const uint16_t* __restrict__ Bt,
    const float* __restrict__ bias, const float* __restrict__ gammas, int gi,
    void* __restrict__ Cp, int K, int Nstore, int Nvalid)
{
    constexpr int BK = 64;
    __shared__ char Atile[128 * 128];
    __shared__ char Btile[128 * 128];

    const int tid  = threadIdx.x;
    const int lane = tid & 63;
    const int wv   = tid >> 6;
    const int wr   = wv >> 1, wc = wv & 1;
    const long long tileM = (long long)blockIdx.y * 128;
    const long long tileN = (long long)blockIdx.x * 128;

    const float g = gammas[gi];

    f32x4 acc[4][4];
#pragma unroll
    for (int m = 0; m < 4; ++m)
#pragma unroll
        for (int n = 0; n < 4; ++n)
            acc[m][n] = (f32x4){0.f, 0.f, 0.f, 0.f};

    const int sr = tid >> 3;
    const int sc = ((tid & 7) * 8) ^ (((tid >> 3) & 7) * 8);
    const uint16_t* Ag = A  + (tileM + sr) * K + sc;
    const uint16_t* Bg = Bt + (tileN + sr) * K + sc;
    char* Ad = Atile + tid * 16;
    char* Bd = Btile + tid * 16;

    const int lr = lane & 15;
    const int klane = (lane >> 4) * 16;
    const int swz = (lr & 7) << 4;

    const int kIters = K / BK;
    for (int kt = 0; kt < kIters; ++kt) {
        const long long k0 = (long long)kt * BK;
        __syncthreads();
#pragma unroll
        for (int i = 0; i < 4; ++i) {
            load_lds16(Ag + (long long)(i * 32) * K + k0, Ad + i * 4096);
            load_lds16(Bg + (long long)(i * 32) * K + k0, Bd + i * 4096);
        }
        __syncthreads();
#pragma unroll
        for (int kk2 = 0; kk2 < 2; ++kk2) {
            const int cb = (kk2 * 64 + klane) ^ swz;
            bf16x8 a[4], b[4];
#pragma unroll
            for (int m = 0; m < 4; ++m)
                a[m] = *(const bf16x8*)(Atile + (wr * 64 + m * 16 + lr) * 128 + cb);
#pragma unroll
            for (int n = 0; n < 4; ++n)
                b[n] = *(const bf16x8*)(Btile + (wc * 64 + n * 16 + lr) * 128 + cb);
#pragma unroll
            for (int m = 0; m < 4; ++m)
#pragma unroll
                for (int n = 0; n < 4; ++n)
                    acc[m][n] = __builtin_amdgcn_mfma_f32_16x16x32_bf16(
                        a[m], b[n], acc[m][n], 0, 0, 0);
        }
    }

    const int cr = (lane >> 4) * 4;
    const int cc = lane & 15;
#pragma unroll
    for (int m = 0; m < 4; ++m) {
        const long long row = tileM + wr * 64 + m * 16 + cr;
#pragma unroll
        for (int n = 0; n < 4; ++n) {
            const int col = (int)tileN + wc * 64 + n * 16 + cc;
            if (col < Nvalid) {
                const float bb = bias[col];
#pragma unroll
                for (int j = 0; j < 4; ++j) {
                    float v = acc[m][n][j] * g + bb;
                    if (RELU) v = fmaxf(v, 0.f);
                    if (BF16OUT)
                        ((uint16_t*)Cp)[(row + j) * (long long)Nstore + col] = f2bf(v);
                    else
                        ((float*)Cp)[(row + j) * (long long)Nstore + col] = v;
                }
            }
        }
    }
}

extern "C" void kernel_launch(void* const* d_in, const int* in_sizes, int n_in,
                              void* d_out, int out_size, void* d_ws, size_t ws_size,
                              hipStream_t stream) {
    const float* x  = (const float*)d_in[0];
    const float* W1 = (const float*)d_in[1];
    const float* b1 = (const float*)d_in[2];
    const float* W2 = (const float*)d_in[3];
    const float* b2 = (const float*)d_in[4];
    const float* W3 = (const float*)d_in[5];
    const float* b3 = (const float*)d_in[6];
    const float* W4 = (const float*)d_in[7];
    const float* b4 = (const float*)d_in[8];
    float* out = (float*)d_out;

    const long long B = 8192, D = 4096, H = 4096, C = 1000, CPAD = 1024;

    char* ws = (char*)d_ws;
    float*  gammas  = (float*)ws;
    double* partial = (double*)(ws + 256);
    uint16_t* Q  = (uint16_t*)(ws + 32768);
    uint16_t* HA = Q  + (size_t)(H * H);
    uint16_t* HB = HA + (size_t)(B * H);

    const long long nW  = H * D;
    const long long nW4 = C * D;

    // stage1 abs-means (4 matrices) + x->bf16 cvt, fused into one launch
    absmean4_cvt<<<dim3(512, 5), 256, 0, stream>>>(W1, W2, W3, W4, partial, x, HA);
    absmean_stage2<<<4, 256, 0, stream>>>(partial, gammas);

    const int gridN = (int)(H / 256);           // 16
    const int nwg   = gridN * (int)(B / 256);   // 512

    quantize_w<<<2048, 256, 0, stream>>>(W1, Q, nW, nW, gammas, 0);
    gemm256<true, true><<<dim3(nwg), dim3(512), 0, stream>>>(
        HA, Q, b1, gammas, 0, HB, (int)D, (int)H, (int)H, gridN);
    quantize_w<<<2048, 256, 0, stream>>>(W2, Q, nW, nW, gammas, 1);
    gemm256<true, true><<<dim3(nwg), dim3(512), 0, stream>>>(
        HB, Q, b2, gammas, 1, HA, (int)H, (int)H, (int)H, gridN);
    quantize_w<<<2048, 256, 0, stream>>>(W3, Q, nW, nW, gammas, 2);
    gemm256<true, true><<<dim3(nwg), dim3(512), 0, stream>>>(
        HA, Q, b3, gammas, 2, HB, (int)H, (int)H, (int)H, gridN);
    quantize_w<<<2048, 256, 0, stream>>>(W4, Q, nW4, CPAD * D, gammas, 3);
    gemm_bt<false, false><<<dim3((unsigned)(CPAD / 128), (unsigned)(B / 128)),
                            dim3(256), 0, stream>>>(
        HB, Q, b4, gammas, 3, out, (int)H, (int)C, (int)C);
}